// Round 6
// baseline (463.496 us; speedup 1.0000x reference)
//
#include <hip/hip_runtime.h>
#include <hip/hip_bf16.h>

// Problem constants
#define BATCH  2
#define SEQ    2048
#define DMODEL 2048
#define NHEADS 32
#define NKV    8
#define HDIM   64
#define ROWS   (BATCH * SEQ)     // 4096
#define NQKV   3072              // 2048 (Q) + 512 (K) + 512 (V)

typedef __attribute__((ext_vector_type(8))) short bf16x8;   // 8 bf16 = 4 VGPRs (MFMA A/B frag)
typedef __attribute__((ext_vector_type(4))) float floatx4;  // MFMA C/D frag

__device__ __forceinline__ float b2f(unsigned short u) {
    union { unsigned int i; float f; } x; x.i = ((unsigned int)u) << 16; return x.f;
}
__device__ __forceinline__ unsigned short f2b(float f) {
    union { float f; unsigned int i; } x; x.f = f;
    unsigned int r = x.i + 0x7fffu + ((x.i >> 16) & 1u);   // RTN-even
    return (unsigned short)(r >> 16);
}
// packed 2xf32 -> 2xbf16 in one dword (v_cvt_pk_bf16_f32), a in low 16 bits
__device__ __forceinline__ unsigned int pkbf(float a, float b) {
    union { __hip_bfloat162 h; unsigned int u; } x;
    x.h = __float22bfloat162_rn(make_float2(a, b));
    return x.u;
}

// async 16B/lane global->LDS. lds ptr must be wave-uniform; lane i lands at +i*16B.
#define GLD16(g, l) __builtin_amdgcn_global_load_lds( \
    (const __attribute__((address_space(1))) unsigned int*)(g), \
    (__attribute__((address_space(3))) unsigned int*)(l), 16, 0, 0)

// ---------------------------------------------------------------------------
// bf16 MFMA GEMM: C[M,N] = A[M,K] @ Bt[N,K]^T.
// T4 counted-vmcnt 3-buffer ring (round-5: verified WIN, ~10us total).
// THIS ROUND: optional fused RoPE epilogue (DO_ROPE) for the QKV GEMM.
// Mapping: lane's acc quadrants c and c+2 hold cols (i, i+32) of one head
// (i = ecol for c=0, ecol+16 for c=1); each wave's 64-col group is one head
// entirely inside Q (scale 0.125), K (scale 1), or V (no-op). Angle uses
// precise sincosf/powf (args up to 2047 rad; fast-math range reduction is
// not sufficient). Replaces the rope_all kernel + its 21 MB round trip.
// ---------------------------------------------------------------------------
template <bool BF16_OUT, bool DO_ROPE>
__global__ __launch_bounds__(256) void mfma_gemm(const unsigned short* __restrict__ A,
                                                 const unsigned short* __restrict__ Bt,
                                                 void* __restrict__ Cout,
                                                 int M, int N, int K) {
    __shared__ unsigned short As[3][128 * 32];  // 3 x 8 KB, [row][k]
    __shared__ unsigned short Bs[3][128 * 32];  // 3 x 8 KB, [n][k]

    const int tid  = threadIdx.x;
    const int wave = tid >> 6;
    const int lane = tid & 63;
    const int m0 = blockIdx.y * 128;
    const int n0 = blockIdx.x * 128;
    const int wr0 = (wave >> 1) * 64;
    const int wc0 = (wave & 1) * 64;

    const int srow = wave * 32 + (lane >> 2);
    const int skc  = (lane & 3) * 8;
    const unsigned short* Ap0 = A  + (size_t)(m0 + srow) * K + skc;
    const unsigned short* Ap1 = Ap0 + (size_t)16 * K;
    const unsigned short* Bp0 = Bt + (size_t)(n0 + srow) * K + skc;
    const unsigned short* Bp1 = Bp0 + (size_t)16 * K;

    const int fr = lane & 15;
    const int fk = (lane >> 4) * 8;

    floatx4 acc[4][4];
    #pragma unroll
    for (int r = 0; r < 4; ++r)
        #pragma unroll
        for (int c = 0; c < 4; ++c)
            #pragma unroll
            for (int g = 0; g < 4; ++g) acc[r][c][g] = 0.f;

    const int NT = K >> 5;   // K-steps of 32

    auto stage = [&](int t, int buf) {
        unsigned short* Ab = &As[buf][wave * 1024];
        unsigned short* Bb = &Bs[buf][wave * 1024];
        const int k0 = t * 32;
        GLD16(Ap0 + k0, Ab);
        GLD16(Ap1 + k0, Ab + 512);
        GLD16(Bp0 + k0, Bb);
        GLD16(Bp1 + k0, Bb + 512);
    };

    // prologue: tiles 0,1 in flight; wait tile 0 only (tile 1 keeps flying)
    stage(0, 0);
    stage(1, 1);
    asm volatile("s_waitcnt vmcnt(4)" ::: "memory");
    __builtin_amdgcn_s_barrier();
    __builtin_amdgcn_sched_barrier(0);

    int cur = 0, nx2 = 2;
    for (int T = 0; T < NT; ++T) {
        if (T + 2 < NT) stage(T + 2, nx2);   // buf holds tile T-1; reads done per prior barrier

        const unsigned short* Asb = &As[cur][0];
        const unsigned short* Bsb = &Bs[cur][0];
        bf16x8 af[4], bfr[4];
        #pragma unroll
        for (int r = 0; r < 4; ++r)
            af[r] = *(const bf16x8*)&Asb[(wr0 + r * 16 + fr) * 32 + fk];
        #pragma unroll
        for (int c = 0; c < 4; ++c)
            bfr[c] = *(const bf16x8*)&Bsb[(wc0 + c * 16 + fr) * 32 + fk];
        #pragma unroll
        for (int r = 0; r < 4; ++r)
            #pragma unroll
            for (int c = 0; c < 4; ++c)
                acc[r][c] = __builtin_amdgcn_mfma_f32_16x16x32_bf16(af[r], bfr[c], acc[r][c], 0, 0, 0);

        if (T + 1 < NT) {
            if (T + 2 < NT)
                asm volatile("s_waitcnt vmcnt(4)" ::: "memory");  // T+1 landed; T+2 flying
            else
                asm volatile("s_waitcnt vmcnt(0)" ::: "memory");  // last tile (once)
            __builtin_amdgcn_s_barrier();
            __builtin_amdgcn_sched_barrier(0);
        }
        cur = (cur == 2) ? 0 : cur + 1;
        nx2 = (nx2 == 2) ? 0 : nx2 + 1;
    }

    const int erow = (lane >> 4) * 4;
    const int ecol = lane & 15;

    if (DO_ROPE) {
        const int colb = n0 + wc0;          // multiple of 64 -> one head, one of Q/K/V
        if (colb < 2560) {                  // Q or K head (V untouched)
            const float scale = (colb < 2048) ? 0.125f : 1.0f;  // 1/sqrt(64) folded into Q
            const float inv0 = powf(10000.0f, -(float)ecol        * (1.0f / 32.0f));
            const float inv1 = powf(10000.0f, -(float)(ecol + 16) * (1.0f / 32.0f));
            #pragma unroll
            for (int r = 0; r < 4; ++r)
                #pragma unroll
                for (int g = 0; g < 4; ++g) {
                    float t = (float)((m0 + wr0 + r * 16 + erow + g) & (SEQ - 1));
                    float s0, c0, s1, c1;
                    sincosf(t * inv0, &s0, &c0);
                    sincosf(t * inv1, &s1, &c1);
                    float a0 = acc[r][0][g], a2 = acc[r][2][g];   // dims (ecol, ecol+32)
                    acc[r][0][g] = (a0 * c0 - a2 * s0) * scale;
                    acc[r][2][g] = (a2 * c0 + a0 * s0) * scale;
                    float a1 = acc[r][1][g], a3 = acc[r][3][g];   // dims (ecol+16, ecol+48)
                    acc[r][1][g] = (a1 * c1 - a3 * s1) * scale;
                    acc[r][3][g] = (a3 * c1 + a1 * s1) * scale;
                }
        }
    }

    #pragma unroll
    for (int r = 0; r < 4; ++r)
        #pragma unroll
        for (int c = 0; c < 4; ++c)
            #pragma unroll
            for (int g = 0; g < 4; ++g) {
                int row = m0 + wr0 + r * 16 + erow + g;
                int col = n0 + wc0 + c * 16 + ecol;
                if (BF16_OUT)
                    ((unsigned short*)Cout)[(size_t)row * N + col] = f2b(acc[r][c][g]);
                else
                    ((float*)Cout)[(size_t)row * N + col] = acc[r][c][g];
            }
}

// ---------------------------------------------------------------------------
// All four weight transpose-casts in one launch. fp32 [2048][N] -> bf16 [N][2048].
// ---------------------------------------------------------------------------
__global__ __launch_bounds__(256) void transpose_cast_all(const float* __restrict__ Wq,
                                                          const float* __restrict__ Wk,
                                                          const float* __restrict__ Wv,
                                                          const float* __restrict__ Wo,
                                                          unsigned short* __restrict__ Wt,
                                                          unsigned short* __restrict__ Wot) {
    __shared__ float t[32][33];
    int bx = blockIdx.x;
    const float* src; unsigned short* dst; int N, nb;
    if (bx < 64)      { src = Wq; dst = Wt;                          N = 2048; nb = bx; }
    else if (bx < 80) { src = Wk; dst = Wt + (size_t)2048 * DMODEL;  N = 512;  nb = bx - 64; }
    else if (bx < 96) { src = Wv; dst = Wt + (size_t)2560 * DMODEL;  N = 512;  nb = bx - 80; }
    else              { src = Wo; dst = Wot;                         N = 2048; nb = bx - 96; }
    const int n0 = nb * 32, k0 = blockIdx.y * 32;
    const int tx = threadIdx.x & 31, ty = threadIdx.x >> 5;
    #pragma unroll
    for (int i = 0; i < 32; i += 8)
        t[ty + i][tx] = src[(size_t)(k0 + ty + i) * N + n0 + tx];
    __syncthreads();
    #pragma unroll
    for (int i = 0; i < 32; i += 8)
        dst[(size_t)(n0 + ty + i) * DMODEL + k0 + tx] = f2b(t[tx][ty + i]);
}

__global__ void cast_f32_to_bf16(const float* __restrict__ src,
                                 unsigned short* __restrict__ dst, int n) {
    int i = (blockIdx.x * 256 + threadIdx.x) * 8;
    if (i >= n) return;
    float4 a = *(const float4*)(src + i);
    float4 b = *(const float4*)(src + i + 4);
    uint4 o;
    o.x = pkbf(a.x, a.y); o.y = pkbf(a.z, a.w);
    o.z = pkbf(b.x, b.y); o.w = pkbf(b.z, b.w);
    *(uint4*)(dst + i) = o;
}

// ---------------------------------------------------------------------------
// MFMA flash attention (causal, GQA) — round-2 shell (best measured), with
// K MOVED OUT OF LDS (this round). Theory: m134 LDS constants give the old
// kernel ~86% LDS-pipe busy (18 b128 reads + stage writes per 16-q wave-iter)
// — LDS data path was the saturated pipe, not MFMA/VALU/HBM. The QK^T
// A-fragment K[j*16+fr][ks*32+fg*8..+7] is 16 CONTIGUOUS bytes in global
// memory -> load directly to registers (global_load_dwordx4), deleting the
// K-stage writes and all 8 Ks b128 reads per iter (~58% LDS busy remains).
// K is 4 MB/batch -> L2-resident; intra-block 4-wave reuse hits L1.
// Fragments for tile kb+1 are reloaded right after QK^T (latency hides under
// exp + PV). LDS: Vts[64][72] + Ps[4][16][72] = 18.4 KB.
// ---------------------------------------------------------------------------
__global__ __launch_bounds__(256, 4) void attn_mfma(const unsigned short* __restrict__ QKV,
                                                    unsigned short* __restrict__ Ctx) {
    __shared__ unsigned short Vts[64][72];   // V^T tile [hd][kpos]
    __shared__ unsigned short Ps[4][16][72]; // per-wave P [q][kpos]

    const int tid  = threadIdx.x;
    const int wave = tid >> 6;
    const int lane = tid & 63;
    const int px = blockIdx.x;      // pair index 0..15
    const int h  = blockIdx.y;
    const int b  = blockIdx.z;
    const int kvh = h >> 2;

    const int fr = lane & 15;        // frag row/col index
    const int fg = lane >> 4;        // frag k-group (0..3)
    const size_t base = (size_t)(b * SEQ) * NQKV;

    // staging maps (tile-independent)
    const int vp2 = tid & 31, vh0 = (tid >> 5) * 8;           // V: kpos pair, 8 hd
    const unsigned short* vbase = QKV + base + (size_t)(2 * vp2) * NQKV + 2560 + kvh * HDIM + vh0;
    // K fragment base: row fr, col fg*8 of the K panel; addr(kb,ks,j) adds
    // (kb*64 + j*16)*NQKV + ks*32.
    const unsigned short* kfrag0 = QKV + base + (size_t)fr * NQKV + 2048 + kvh * HDIM + fg * 8;

    #pragma unroll 1
    for (int t = 0; t < 2; ++t) {
        const int qb = (t == 0) ? (31 - px) : px;   // big tile first
        const int wbase = qb * 64 + wave * 16;

        // Q fragments (B-operand of S^T): B[n=q=fr][k=fg*8..]
        bf16x8 qf[2];
        #pragma unroll
        for (int ks = 0; ks < 2; ++ks)
            qf[ks] = *(const bf16x8*)(QKV + base + (size_t)(wbase + fr) * NQKV
                                      + h * HDIM + ks * 32 + fg * 8);

        float l = 0.f;
        floatx4 acc[4];   // O^T [hd-tile j2]
        #pragma unroll
        for (int j2 = 0; j2 < 4; ++j2)
            #pragma unroll
            for (int g = 0; g < 4; ++g) acc[j2][g] = 0.f;

        const int nkb = qb + 1;

        // prefetch tile 0: K fragments to registers + V rows
        bf16x8 kf[2][4];
        #pragma unroll
        for (int ks = 0; ks < 2; ++ks)
            #pragma unroll
            for (int j = 0; j < 4; ++j)
                kf[ks][j] = *(const bf16x8*)(kfrag0 + (size_t)(j * 16) * NQKV + ks * 32);
        bf16x8 v0 = *(const bf16x8*)vbase;
        bf16x8 v1 = *(const bf16x8*)(vbase + NQKV);

        for (int kb = 0; kb < nkb; ++kb) {
            __syncthreads();                       // prior iter done reading LDS
            #pragma unroll
            for (int j = 0; j < 8; ++j) {          // packed-pair transpose write
                unsigned int w = (unsigned int)(unsigned short)v0[j]
                               | ((unsigned int)(unsigned short)v1[j] << 16);
                *(unsigned int*)&Vts[vh0 + j][2 * vp2] = w;
            }
            // issue next tile's V loads (land during this tile's compute)
            {
                int nx = (kb + 1 < nkb) ? kb + 1 : kb;
                const unsigned short* vp = vbase + (size_t)(nx * 64) * NQKV;
                v0 = *(const bf16x8*)vp;
                v1 = *(const bf16x8*)(vp + NQKV);
            }
            __syncthreads();

            const bool skip = (kb * 64 > wbase + 15);          // tile fully above diagonal
            const bool needMask = (kb * 64 + 63 > wbase);      // tile touches diagonal

            floatx4 sc[4];   // [kpos-tile j]
            if (!skip) {
                // ---- S^T = K Q^T : D[m=kpos][n=q] ----
                #pragma unroll
                for (int j = 0; j < 4; ++j)
                    #pragma unroll
                    for (int g = 0; g < 4; ++g) sc[j][g] = 0.f;
                __builtin_amdgcn_s_setprio(1);
                #pragma unroll
                for (int ks = 0; ks < 2; ++ks)
                    #pragma unroll
                    for (int j = 0; j < 4; ++j)
                        sc[j] = __builtin_amdgcn_mfma_f32_16x16x32_bf16(kf[ks][j], qf[ks], sc[j], 0, 0, 0);
                __builtin_amdgcn_s_setprio(0);
            }

            // reload K fragments for the next tile (after QK^T consumed kf;
            // load latency hides under exp + PV below)
            {
                int nx = (kb + 1 < nkb) ? kb + 1 : kb;
                const unsigned short* kp = kfrag0 + (size_t)(nx * 64) * NQKV;
                #pragma unroll
                for (int ks = 0; ks < 2; ++ks)
                    #pragma unroll
                    for (int j = 0; j < 4; ++j)
                        kf[ks][j] = *(const bf16x8*)(kp + (size_t)(j * 16) * NQKV + ks * 32);
            }

            if (!skip) {
                if (needMask) {
                    int qi = wbase + fr;
                    #pragma unroll
                    for (int j = 0; j < 4; ++j)
                        #pragma unroll
                        for (int g = 0; g < 4; ++g) {
                            int kj = kb * 64 + j * 16 + fg * 4 + g;
                            if (kj > qi) sc[j][g] = -1e30f;
                        }
                }

                // ---- exp + per-lane partial l; P -> per-wave LDS (no shuffles) ----
                #pragma unroll
                for (int j = 0; j < 4; ++j) {
                    #pragma unroll
                    for (int g = 0; g < 4; ++g) {
                        float e = __expf(sc[j][g]);   // masked -> exp(-1e30) = 0
                        sc[j][g] = e;
                        l += e;
                    }
                    uint2 w;
                    w.x = pkbf(sc[j][0], sc[j][1]);
                    w.y = pkbf(sc[j][2], sc[j][3]);
                    *(uint2*)&Ps[wave][fr][j * 16 + fg * 4] = w;
                }

                // ---- O^T += V^T P^T : A = V^T[hd][kpos], B = P[q][kpos] ----
                __builtin_amdgcn_s_setprio(1);
                #pragma unroll
                for (int ks = 0; ks < 2; ++ks) {
                    bf16x8 pf = *(const bf16x8*)&Ps[wave][fr][ks * 32 + fg * 8];
                    #pragma unroll
                    for (int j2 = 0; j2 < 4; ++j2) {
                        bf16x8 vf = *(const bf16x8*)&Vts[j2 * 16 + fr][ks * 32 + fg * 8];
                        acc[j2] = __builtin_amdgcn_mfma_f32_16x16x32_bf16(vf, pf, acc[j2], 0, 0, 0);
                    }
                }
                __builtin_amdgcn_s_setprio(0);
            }
        }

        // epilogue: reduce l across the 4 fg-lanes of each q, normalize, store
        {
            float lt = l;
            lt += __shfl_xor(lt, 16);
            lt += __shfl_xor(lt, 32);
            float inv = 1.0f / lt;
            int q = wbase + fr;
            unsigned short* cp = Ctx + (size_t)(b * SEQ + q) * DMODEL + h * HDIM;
            #pragma unroll
            for (int j2 = 0; j2 < 4; ++j2) {
                uint2 w;
                w.x = pkbf(acc[j2][0] * inv, acc[j2][1] * inv);
                w.y = pkbf(acc[j2][2] * inv, acc[j2][3] * inv);
                *(uint2*)(cp + j2 * 16 + fg * 4) = w;
            }
        }
    }
}

// ---------------------------------------------------------------------------
extern "C" void kernel_launch(void* const* d_in, const int* in_sizes, int n_in,
                              void* d_out, int out_size, void* d_ws, size_t ws_size,
                              hipStream_t stream) {
    const float* X  = (const float*)d_in[0];
    const float* Wq = (const float*)d_in[1];
    const float* Wk = (const float*)d_in[2];
    const float* Wv = (const float*)d_in[3];
    const float* Wo = (const float*)d_in[4];
    float* out = (float*)d_out;

    unsigned short* Xb   = (unsigned short*)d_ws;                 // [4096][2048]
    unsigned short* Wt   = Xb + (size_t)ROWS * DMODEL;            // [3072][2048]
    unsigned short* Wot  = Wt + (size_t)NQKV * DMODEL;            // [2048][2048]
    unsigned short* QKVb = Wot + (size_t)DMODEL * DMODEL;         // [4096][3072]
    unsigned short* Ctxb = QKVb + (size_t)ROWS * NQKV;            // [4096][2048]

    cast_f32_to_bf16<<<(ROWS * DMODEL) / (8 * 256), 256, 0, stream>>>(X, Xb, ROWS * DMODEL);
    transpose_cast_all<<<dim3(160, 64), 256, 0, stream>>>(Wq, Wk, Wv, Wo, Wt, Wot);

    // QKV projection with fused RoPE (replaces the separate rope_all pass)
    mfma_gemm<true, true><<<dim3(NQKV / 128, ROWS / 128), 256, 0, stream>>>(Xb, Wt, QKVb, ROWS, NQKV, DMODEL);

    attn_mfma<<<dim3(SEQ / 128, NHEADS, BATCH), 256, 0, stream>>>(QKVb, Ctxb);

    mfma_gemm<false, false><<<dim3(DMODEL / 128, ROWS / 128), 256, 0, stream>>>(Ctxb, Wot, out, ROWS, DMODEL, DMODEL);
}

// Round 7
// 336.630 us; speedup vs baseline: 1.3769x; 1.3769x over previous
//
#include <hip/hip_runtime.h>
#include <hip/hip_bf16.h>

// Problem constants
#define BATCH  2
#define SEQ    2048
#define DMODEL 2048
#define NHEADS 32
#define NKV    8
#define HDIM   64
#define ROWS   (BATCH * SEQ)     // 4096
#define NQKV   3072              // 2048 (Q) + 512 (K) + 512 (V)

typedef __attribute__((ext_vector_type(8))) short bf16x8;   // 8 bf16 = 4 VGPRs (MFMA A/B frag)
typedef __attribute__((ext_vector_type(4))) float floatx4;  // MFMA C/D frag

__device__ __forceinline__ float b2f(unsigned short u) {
    union { unsigned int i; float f; } x; x.i = ((unsigned int)u) << 16; return x.f;
}
__device__ __forceinline__ unsigned short f2b(float f) {
    union { float f; unsigned int i; } x; x.f = f;
    unsigned int r = x.i + 0x7fffu + ((x.i >> 16) & 1u);   // RTN-even
    return (unsigned short)(r >> 16);
}
// packed 2xf32 -> 2xbf16 in one dword (v_cvt_pk_bf16_f32), a in low 16 bits
__device__ __forceinline__ unsigned int pkbf(float a, float b) {
    union { __hip_bfloat162 h; unsigned int u; } x;
    x.h = __float22bfloat162_rn(make_float2(a, b));
    return x.u;
}

// async 16B/lane global->LDS. lds ptr must be wave-uniform; lane i lands at +i*16B.
#define GLD16(g, l) __builtin_amdgcn_global_load_lds( \
    (const __attribute__((address_space(1))) unsigned int*)(g), \
    (__attribute__((address_space(3))) unsigned int*)(l), 16, 0, 0)

// ---------------------------------------------------------------------------
// RoPE cos/sin table: tab[t*32 + i] = (cos(t*f_i), sin(t*f_i)).
// Precise powf/sincosf once (65k threads, ~2us) instead of per-GEMM-element.
// ---------------------------------------------------------------------------
__global__ void rope_table(float2* __restrict__ tab) {
    int idx = blockIdx.x * 256 + threadIdx.x;   // 65536 = 2048 t x 32 i
    int i = idx & 31, t = idx >> 5;
    float inv = powf(10000.0f, -(float)i * (1.0f / 32.0f));
    float s, c;
    sincosf((float)t * inv, &s, &c);
    tab[idx] = make_float2(c, s);
}

// ---------------------------------------------------------------------------
// bf16 MFMA GEMM: C[M,N] = A[M,K] @ Bt[N,K]^T.
// T4 counted-vmcnt 3-buffer ring (round-5: verified WIN).
// DO_ROPE: fused RoPE epilogue for the QKV GEMM using the precomputed table
// (round-6 validated the quadrant mapping; the cost was the per-element
// powf/sincosf, now replaced by 2 table loads). Q scaled by 0.125.
// ---------------------------------------------------------------------------
template <bool BF16_OUT, bool DO_ROPE>
__global__ __launch_bounds__(256) void mfma_gemm(const unsigned short* __restrict__ A,
                                                 const unsigned short* __restrict__ Bt,
                                                 void* __restrict__ Cout,
                                                 const float2* __restrict__ rtab,
                                                 int M, int N, int K) {
    __shared__ unsigned short As[3][128 * 32];  // 3 x 8 KB, [row][k]
    __shared__ unsigned short Bs[3][128 * 32];  // 3 x 8 KB, [n][k]

    const int tid  = threadIdx.x;
    const int wave = tid >> 6;
    const int lane = tid & 63;
    const int m0 = blockIdx.y * 128;
    const int n0 = blockIdx.x * 128;
    const int wr0 = (wave >> 1) * 64;
    const int wc0 = (wave & 1) * 64;

    const int srow = wave * 32 + (lane >> 2);
    const int skc  = (lane & 3) * 8;
    const unsigned short* Ap0 = A  + (size_t)(m0 + srow) * K + skc;
    const unsigned short* Ap1 = Ap0 + (size_t)16 * K;
    const unsigned short* Bp0 = Bt + (size_t)(n0 + srow) * K + skc;
    const unsigned short* Bp1 = Bp0 + (size_t)16 * K;

    const int fr = lane & 15;
    const int fk = (lane >> 4) * 8;

    floatx4 acc[4][4];
    #pragma unroll
    for (int r = 0; r < 4; ++r)
        #pragma unroll
        for (int c = 0; c < 4; ++c)
            #pragma unroll
            for (int g = 0; g < 4; ++g) acc[r][c][g] = 0.f;

    const int NT = K >> 5;   // K-steps of 32

    auto stage = [&](int t, int buf) {
        unsigned short* Ab = &As[buf][wave * 1024];
        unsigned short* Bb = &Bs[buf][wave * 1024];
        const int k0 = t * 32;
        GLD16(Ap0 + k0, Ab);
        GLD16(Ap1 + k0, Ab + 512);
        GLD16(Bp0 + k0, Bb);
        GLD16(Bp1 + k0, Bb + 512);
    };

    // prologue: tiles 0,1 in flight; wait tile 0 only (tile 1 keeps flying)
    stage(0, 0);
    stage(1, 1);
    asm volatile("s_waitcnt vmcnt(4)" ::: "memory");
    __builtin_amdgcn_s_barrier();
    __builtin_amdgcn_sched_barrier(0);

    int cur = 0, nx2 = 2;
    for (int T = 0; T < NT; ++T) {
        if (T + 2 < NT) stage(T + 2, nx2);   // buf holds tile T-1; reads done per prior barrier

        const unsigned short* Asb = &As[cur][0];
        const unsigned short* Bsb = &Bs[cur][0];
        bf16x8 af[4], bfr[4];
        #pragma unroll
        for (int r = 0; r < 4; ++r)
            af[r] = *(const bf16x8*)&Asb[(wr0 + r * 16 + fr) * 32 + fk];
        #pragma unroll
        for (int c = 0; c < 4; ++c)
            bfr[c] = *(const bf16x8*)&Bsb[(wc0 + c * 16 + fr) * 32 + fk];
        #pragma unroll
        for (int r = 0; r < 4; ++r)
            #pragma unroll
            for (int c = 0; c < 4; ++c)
                acc[r][c] = __builtin_amdgcn_mfma_f32_16x16x32_bf16(af[r], bfr[c], acc[r][c], 0, 0, 0);

        if (T + 1 < NT) {
            if (T + 2 < NT)
                asm volatile("s_waitcnt vmcnt(4)" ::: "memory");  // T+1 landed; T+2 flying
            else
                asm volatile("s_waitcnt vmcnt(0)" ::: "memory");  // last tile (once)
            __builtin_amdgcn_s_barrier();
            __builtin_amdgcn_sched_barrier(0);
        }
        cur = (cur == 2) ? 0 : cur + 1;
        nx2 = (nx2 == 2) ? 0 : nx2 + 1;
    }

    const int erow = (lane >> 4) * 4;
    const int ecol = lane & 15;

    if (DO_ROPE) {
        const int colb = n0 + wc0;          // multiple of 64 -> one head, one of Q/K/V
        if (colb < 2560) {                  // Q or K head (V untouched)
            const float scale = (colb < 2048) ? 0.125f : 1.0f;  // 1/sqrt(64) folded into Q
            #pragma unroll
            for (int r = 0; r < 4; ++r)
                #pragma unroll
                for (int g = 0; g < 4; ++g) {
                    int t = (m0 + wr0 + r * 16 + erow + g) & (SEQ - 1);
                    float2 cs0 = rtab[t * 32 + ecol];
                    float2 cs1 = rtab[t * 32 + ecol + 16];
                    float a0 = acc[r][0][g], a2 = acc[r][2][g];   // dims (ecol, ecol+32)
                    acc[r][0][g] = (a0 * cs0.x - a2 * cs0.y) * scale;
                    acc[r][2][g] = (a2 * cs0.x + a0 * cs0.y) * scale;
                    float a1 = acc[r][1][g], a3 = acc[r][3][g];   // dims (ecol+16, ecol+48)
                    acc[r][1][g] = (a1 * cs1.x - a3 * cs1.y) * scale;
                    acc[r][3][g] = (a3 * cs1.x + a1 * cs1.y) * scale;
                }
        }
    }

    #pragma unroll
    for (int r = 0; r < 4; ++r)
        #pragma unroll
        for (int c = 0; c < 4; ++c)
            #pragma unroll
            for (int g = 0; g < 4; ++g) {
                int row = m0 + wr0 + r * 16 + erow + g;
                int col = n0 + wc0 + c * 16 + ecol;
                if (BF16_OUT)
                    ((unsigned short*)Cout)[(size_t)row * N + col] = f2b(acc[r][c][g]);
                else
                    ((float*)Cout)[(size_t)row * N + col] = acc[r][c][g];
            }
}

// ---------------------------------------------------------------------------
// All four weight transpose-casts in one launch. fp32 [2048][N] -> bf16 [N][2048].
// ---------------------------------------------------------------------------
__global__ __launch_bounds__(256) void transpose_cast_all(const float* __restrict__ Wq,
                                                          const float* __restrict__ Wk,
                                                          const float* __restrict__ Wv,
                                                          const float* __restrict__ Wo,
                                                          unsigned short* __restrict__ Wt,
                                                          unsigned short* __restrict__ Wot) {
    __shared__ float t[32][33];
    int bx = blockIdx.x;
    const float* src; unsigned short* dst; int N, nb;
    if (bx < 64)      { src = Wq; dst = Wt;                          N = 2048; nb = bx; }
    else if (bx < 80) { src = Wk; dst = Wt + (size_t)2048 * DMODEL;  N = 512;  nb = bx - 64; }
    else if (bx < 96) { src = Wv; dst = Wt + (size_t)2560 * DMODEL;  N = 512;  nb = bx - 80; }
    else              { src = Wo; dst = Wot;                         N = 2048; nb = bx - 96; }
    const int n0 = nb * 32, k0 = blockIdx.y * 32;
    const int tx = threadIdx.x & 31, ty = threadIdx.x >> 5;
    #pragma unroll
    for (int i = 0; i < 32; i += 8)
        t[ty + i][tx] = src[(size_t)(k0 + ty + i) * N + n0 + tx];
    __syncthreads();
    #pragma unroll
    for (int i = 0; i < 32; i += 8)
        dst[(size_t)(n0 + ty + i) * DMODEL + k0 + tx] = f2b(t[tx][ty + i]);
}

__global__ void cast_f32_to_bf16(const float* __restrict__ src,
                                 unsigned short* __restrict__ dst, int n) {
    int i = (blockIdx.x * 256 + threadIdx.x) * 8;
    if (i >= n) return;
    float4 a = *(const float4*)(src + i);
    float4 b = *(const float4*)(src + i + 4);
    uint4 o;
    o.x = pkbf(a.x, a.y); o.y = pkbf(a.z, a.w);
    o.z = pkbf(b.x, b.y); o.w = pkbf(b.z, b.w);
    *(uint4*)(dst + i) = o;
}

// ---------------------------------------------------------------------------
// MFMA flash attention (causal, GQA) — round-2/5 verified shell (79.4us),
// THIS ROUND: single-barrier double-buffered K/V LDS.
// Old: 2 __syncthreads per k-iter (write->read fence + read->overwrite fence
// on the single buffer). New: Ks[2]/Vts[2]; iter kb writes buf[kb&1], ONE
// barrier, computes from buf[kb&1]. Hazard ledger: buf written in kb was
// last read in kb-2 (fenced by kb-1's barrier); write->read same iter fenced
// by this iter's barrier; extra barrier after the kb-loop fences the t=0->t=1
// buffer reuse. Barriers outside all wave-divergent branches. LDS 45 KB ->
// 3 blocks/CU (= measured residency anyway). Round-6's K-in-registers is
// REVERTED (latency-bound regression: scattered per-wave global loads).
// ---------------------------------------------------------------------------
__global__ __launch_bounds__(256, 3) void attn_mfma(const unsigned short* __restrict__ QKV,
                                                    unsigned short* __restrict__ Ctx) {
    __shared__ unsigned short Ks[2][64][72];    // K tile [buf][kpos][hd]
    __shared__ unsigned short Vts[2][64][72];   // V^T tile [buf][hd][kpos]
    __shared__ unsigned short Ps[4][16][72];    // per-wave P [q][kpos]

    const int tid  = threadIdx.x;
    const int wave = tid >> 6;
    const int lane = tid & 63;
    const int px = blockIdx.x;      // pair index 0..15
    const int h  = blockIdx.y;
    const int b  = blockIdx.z;
    const int kvh = h >> 2;

    const int fr = lane & 15;        // frag row/col index
    const int fg = lane >> 4;        // frag k-group (0..3)
    const size_t base = (size_t)(b * SEQ) * NQKV;

    // staging maps (tile-independent)
    const int krow = tid >> 2, kc0 = (tid & 3) * 16;          // K: 1 row, 32 B
    const int vp2 = tid & 31, vh0 = (tid >> 5) * 8;           // V: kpos pair, 8 hd
    const unsigned short* kbase = QKV + base + (size_t)krow * NQKV + 2048 + kvh * HDIM + kc0;
    const unsigned short* vbase = QKV + base + (size_t)(2 * vp2) * NQKV + 2560 + kvh * HDIM + vh0;

    #pragma unroll 1
    for (int t = 0; t < 2; ++t) {
        const int qb = (t == 0) ? (31 - px) : px;   // big tile first
        const int wbase = qb * 64 + wave * 16;

        // Q fragments (B-operand of S^T): B[n=q=fr][k=fg*8..]
        bf16x8 qf[2];
        #pragma unroll
        for (int ks = 0; ks < 2; ++ks)
            qf[ks] = *(const bf16x8*)(QKV + base + (size_t)(wbase + fr) * NQKV
                                      + h * HDIM + ks * 32 + fg * 8);

        float l = 0.f;
        floatx4 acc[4];   // O^T [hd-tile j2]
        #pragma unroll
        for (int j2 = 0; j2 < 4; ++j2)
            #pragma unroll
            for (int g = 0; g < 4; ++g) acc[j2][g] = 0.f;

        const int nkb = qb + 1;

        // prefetch tile 0
        bf16x8 kr0 = *(const bf16x8*)kbase;
        bf16x8 kr1 = *(const bf16x8*)(kbase + 8);
        bf16x8 v0  = *(const bf16x8*)vbase;
        bf16x8 v1  = *(const bf16x8*)(vbase + NQKV);

        for (int kb = 0; kb < nkb; ++kb) {
            const int pb = kb & 1;
            // (1) write current tile into buf[pb] (last read in kb-2, fenced by kb-1's barrier)
            *(bf16x8*)&Ks[pb][krow][kc0]     = kr0;
            *(bf16x8*)&Ks[pb][krow][kc0 + 8] = kr1;
            #pragma unroll
            for (int j = 0; j < 8; ++j) {          // packed-pair transpose write
                unsigned int w = (unsigned int)(unsigned short)v0[j]
                               | ((unsigned int)(unsigned short)v1[j] << 16);
                *(unsigned int*)&Vts[pb][vh0 + j][2 * vp2] = w;
            }
            // (2) issue next tile's global loads (land during this tile's compute)
            {
                int nx = (kb + 1 < nkb) ? kb + 1 : kb;
                const unsigned short* kp = kbase + (size_t)(nx * 64) * NQKV;
                const unsigned short* vp = vbase + (size_t)(nx * 64) * NQKV;
                kr0 = *(const bf16x8*)kp;
                kr1 = *(const bf16x8*)(kp + 8);
                v0  = *(const bf16x8*)vp;
                v1  = *(const bf16x8*)(vp + NQKV);
            }
            // (3) single barrier: makes buf[pb] visible to all waves
            __syncthreads();

            const bool skip = (kb * 64 > wbase + 15);          // tile fully above diagonal
            if (!skip) {
                const bool needMask = (kb * 64 + 63 > wbase);  // tile touches diagonal

                // ---- S^T = K Q^T : D[m=kpos][n=q] ----
                floatx4 sc[4];   // [kpos-tile j]
                #pragma unroll
                for (int j = 0; j < 4; ++j)
                    #pragma unroll
                    for (int g = 0; g < 4; ++g) sc[j][g] = 0.f;
                __builtin_amdgcn_s_setprio(1);
                #pragma unroll
                for (int ks = 0; ks < 2; ++ks) {
                    #pragma unroll
                    for (int j = 0; j < 4; ++j) {
                        bf16x8 kf = *(const bf16x8*)&Ks[pb][j * 16 + fr][ks * 32 + fg * 8];
                        sc[j] = __builtin_amdgcn_mfma_f32_16x16x32_bf16(kf, qf[ks], sc[j], 0, 0, 0);
                    }
                }
                __builtin_amdgcn_s_setprio(0);

                if (needMask) {
                    int qi = wbase + fr;
                    #pragma unroll
                    for (int j = 0; j < 4; ++j)
                        #pragma unroll
                        for (int g = 0; g < 4; ++g) {
                            int kj = kb * 64 + j * 16 + fg * 4 + g;
                            if (kj > qi) sc[j][g] = -1e30f;
                        }
                }

                // ---- exp + per-lane partial l; P -> per-wave LDS (no shuffles) ----
                #pragma unroll
                for (int j = 0; j < 4; ++j) {
                    #pragma unroll
                    for (int g = 0; g < 4; ++g) {
                        float e = __expf(sc[j][g]);   // masked -> exp(-1e30) = 0
                        sc[j][g] = e;
                        l += e;
                    }
                    uint2 w;
                    w.x = pkbf(sc[j][0], sc[j][1]);
                    w.y = pkbf(sc[j][2], sc[j][3]);
                    *(uint2*)&Ps[wave][fr][j * 16 + fg * 4] = w;
                }

                // ---- O^T += V^T P^T : A = V^T[hd][kpos], B = P[q][kpos] ----
                __builtin_amdgcn_s_setprio(1);
                #pragma unroll
                for (int ks = 0; ks < 2; ++ks) {
                    bf16x8 pf = *(const bf16x8*)&Ps[wave][fr][ks * 32 + fg * 8];
                    #pragma unroll
                    for (int j2 = 0; j2 < 4; ++j2) {
                        bf16x8 vf = *(const bf16x8*)&Vts[pb][j2 * 16 + fr][ks * 32 + fg * 8];
                        acc[j2] = __builtin_amdgcn_mfma_f32_16x16x32_bf16(vf, pf, acc[j2], 0, 0, 0);
                    }
                }
                __builtin_amdgcn_s_setprio(0);
            }
        }
        // fence t=0's last reads before t=1 reuses the buffers
        __syncthreads();

        // epilogue: reduce l across the 4 fg-lanes of each q, normalize, store
        {
            float lt = l;
            lt += __shfl_xor(lt, 16);
            lt += __shfl_xor(lt, 32);
            float inv = 1.0f / lt;
            int q = wbase + fr;
            unsigned short* cp = Ctx + (size_t)(b * SEQ + q) * DMODEL + h * HDIM;
            #pragma unroll
            for (int j2 = 0; j2 < 4; ++j2) {
                uint2 w;
                w.x = pkbf(acc[j2][0] * inv, acc[j2][1] * inv);
                w.y = pkbf(acc[j2][2] * inv, acc[j2][3] * inv);
                *(uint2*)(cp + j2 * 16 + fg * 4) = w;
            }
        }
    }
}

// ---------------------------------------------------------------------------
extern "C" void kernel_launch(void* const* d_in, const int* in_sizes, int n_in,
                              void* d_out, int out_size, void* d_ws, size_t ws_size,
                              hipStream_t stream) {
    const float* X  = (const float*)d_in[0];
    const float* Wq = (const float*)d_in[1];
    const float* Wk = (const float*)d_in[2];
    const float* Wv = (const float*)d_in[3];
    const float* Wo = (const float*)d_in[4];
    float* out = (float*)d_out;

    unsigned short* Xb   = (unsigned short*)d_ws;                 // [4096][2048]
    unsigned short* Wt   = Xb + (size_t)ROWS * DMODEL;            // [3072][2048]
    unsigned short* Wot  = Wt + (size_t)NQKV * DMODEL;            // [2048][2048]
    unsigned short* QKVb = Wot + (size_t)DMODEL * DMODEL;         // [4096][3072]
    unsigned short* Ctxb = QKVb + (size_t)ROWS * NQKV;            // [4096][2048]
    float2* Rtab = (float2*)(Ctxb + (size_t)ROWS * DMODEL);       // [2048][32] cos/sin

    rope_table<<<256, 256, 0, stream>>>(Rtab);
    cast_f32_to_bf16<<<(ROWS * DMODEL) / (8 * 256), 256, 0, stream>>>(X, Xb, ROWS * DMODEL);
    transpose_cast_all<<<dim3(160, 64), 256, 0, stream>>>(Wq, Wk, Wv, Wo, Wt, Wot);

    // QKV projection with fused table-RoPE (replaces the separate rope_all pass)
    mfma_gemm<true, true><<<dim3(NQKV / 128, ROWS / 128), 256, 0, stream>>>(Xb, Wt, QKVb, Rtab, ROWS, NQKV, DMODEL);

    attn_mfma<<<dim3(SEQ / 128, NHEADS, BATCH), 256, 0, stream>>>(QKVb, Ctxb);

    mfma_gemm<false, false><<<dim3(DMODEL / 128, ROWS / 128), 256, 0, stream>>>(Ctxb, Wot, out, Rtab, ROWS, DMODEL, DMODEL);
}

// Round 8
// 326.884 us; speedup vs baseline: 1.4179x; 1.0298x over previous
//
#include <hip/hip_runtime.h>
#include <hip/hip_bf16.h>

// Problem constants
#define BATCH  2
#define SEQ    2048
#define DMODEL 2048
#define NHEADS 32
#define NKV    8
#define HDIM   64
#define ROWS   (BATCH * SEQ)     // 4096
#define NQKV   3072              // 2048 (Q) + 512 (K) + 512 (V)

typedef __attribute__((ext_vector_type(8))) short bf16x8;   // 8 bf16 = 4 VGPRs (MFMA A/B frag)
typedef __attribute__((ext_vector_type(4))) float floatx4;  // MFMA C/D frag

__device__ __forceinline__ float b2f(unsigned short u) {
    union { unsigned int i; float f; } x; x.i = ((unsigned int)u) << 16; return x.f;
}
__device__ __forceinline__ unsigned short f2b(float f) {
    union { float f; unsigned int i; } x; x.f = f;
    unsigned int r = x.i + 0x7fffu + ((x.i >> 16) & 1u);   // RTN-even
    return (unsigned short)(r >> 16);
}
// packed 2xf32 -> 2xbf16 in one dword (v_cvt_pk_bf16_f32), a in low 16 bits
__device__ __forceinline__ unsigned int pkbf(float a, float b) {
    union { __hip_bfloat162 h; unsigned int u; } x;
    x.h = __float22bfloat162_rn(make_float2(a, b));
    return x.u;
}

// async 16B/lane global->LDS. lds ptr must be wave-uniform; lane i lands at +i*16B.
#define GLD16(g, l) __builtin_amdgcn_global_load_lds( \
    (const __attribute__((address_space(1))) unsigned int*)(g), \
    (__attribute__((address_space(3))) unsigned int*)(l), 16, 0, 0)

// ---------------------------------------------------------------------------
// bf16 MFMA GEMM: C[M,N] = A[M,K] @ Bt[N,K]^T.
// T4 counted-vmcnt 3-buffer ring (round-5 verified: both GEMMs < 79.4us).
// ROUND 8: RoPE fusion REVERTED (r6 powf epilogue +49us, r7 table epilogue
// +26us — both cost more than the 10us standalone rope_all; scattered loads
// against 64 live acc VGPRs serialize at L2 latency). NEW: bijective
// XCD-aware block swizzle (T1) — r7 measured FETCH 83MB vs 29MB ideal (2.8x
// L2 overfetch with default round-robin). nwg%8==0 for both grids (768, 512).
// ---------------------------------------------------------------------------
template <bool BF16_OUT>
__global__ __launch_bounds__(256) void mfma_gemm(const unsigned short* __restrict__ A,
                                                 const unsigned short* __restrict__ Bt,
                                                 void* __restrict__ Cout,
                                                 int M, int N, int K) {
    __shared__ unsigned short As[3][128 * 32];  // 3 x 8 KB, [row][k]
    __shared__ unsigned short Bs[3][128 * 32];  // 3 x 8 KB, [n][k]

    const int tid  = threadIdx.x;
    const int wave = tid >> 6;
    const int lane = tid & 63;

    // XCD-aware bijective swizzle of the flattened block id (nwg % 8 == 0):
    // blocks resident on one XCD become consecutive in row-major tile order,
    // sharing A-row panels in that XCD's private L2.
    const int nwg  = gridDim.x * gridDim.y;
    const int wgid = blockIdx.y * gridDim.x + blockIdx.x;
    const int swz  = (wgid & 7) * (nwg >> 3) + (wgid >> 3);
    const int m0 = (swz / gridDim.x) * 128;
    const int n0 = (swz % gridDim.x) * 128;

    const int wr0 = (wave >> 1) * 64;
    const int wc0 = (wave & 1) * 64;

    const int srow = wave * 32 + (lane >> 2);
    const int skc  = (lane & 3) * 8;
    const unsigned short* Ap0 = A  + (size_t)(m0 + srow) * K + skc;
    const unsigned short* Ap1 = Ap0 + (size_t)16 * K;
    const unsigned short* Bp0 = Bt + (size_t)(n0 + srow) * K + skc;
    const unsigned short* Bp1 = Bp0 + (size_t)16 * K;

    const int fr = lane & 15;
    const int fk = (lane >> 4) * 8;

    floatx4 acc[4][4];
    #pragma unroll
    for (int r = 0; r < 4; ++r)
        #pragma unroll
        for (int c = 0; c < 4; ++c)
            #pragma unroll
            for (int g = 0; g < 4; ++g) acc[r][c][g] = 0.f;

    const int NT = K >> 5;   // K-steps of 32

    auto stage = [&](int t, int buf) {
        unsigned short* Ab = &As[buf][wave * 1024];
        unsigned short* Bb = &Bs[buf][wave * 1024];
        const int k0 = t * 32;
        GLD16(Ap0 + k0, Ab);
        GLD16(Ap1 + k0, Ab + 512);
        GLD16(Bp0 + k0, Bb);
        GLD16(Bp1 + k0, Bb + 512);
    };

    // prologue: tiles 0,1 in flight; wait tile 0 only (tile 1 keeps flying)
    stage(0, 0);
    stage(1, 1);
    asm volatile("s_waitcnt vmcnt(4)" ::: "memory");
    __builtin_amdgcn_s_barrier();
    __builtin_amdgcn_sched_barrier(0);

    int cur = 0, nx2 = 2;
    for (int T = 0; T < NT; ++T) {
        if (T + 2 < NT) stage(T + 2, nx2);   // buf holds tile T-1; reads done per prior barrier

        const unsigned short* Asb = &As[cur][0];
        const unsigned short* Bsb = &Bs[cur][0];
        bf16x8 af[4], bfr[4];
        #pragma unroll
        for (int r = 0; r < 4; ++r)
            af[r] = *(const bf16x8*)&Asb[(wr0 + r * 16 + fr) * 32 + fk];
        #pragma unroll
        for (int c = 0; c < 4; ++c)
            bfr[c] = *(const bf16x8*)&Bsb[(wc0 + c * 16 + fr) * 32 + fk];
        #pragma unroll
        for (int r = 0; r < 4; ++r)
            #pragma unroll
            for (int c = 0; c < 4; ++c)
                acc[r][c] = __builtin_amdgcn_mfma_f32_16x16x32_bf16(af[r], bfr[c], acc[r][c], 0, 0, 0);

        if (T + 1 < NT) {
            if (T + 2 < NT)
                asm volatile("s_waitcnt vmcnt(4)" ::: "memory");  // T+1 landed; T+2 flying
            else
                asm volatile("s_waitcnt vmcnt(0)" ::: "memory");  // last tile (once)
            __builtin_amdgcn_s_barrier();
            __builtin_amdgcn_sched_barrier(0);
        }
        cur = (cur == 2) ? 0 : cur + 1;
        nx2 = (nx2 == 2) ? 0 : nx2 + 1;
    }

    const int erow = (lane >> 4) * 4;
    const int ecol = lane & 15;
    #pragma unroll
    for (int r = 0; r < 4; ++r)
        #pragma unroll
        for (int c = 0; c < 4; ++c)
            #pragma unroll
            for (int g = 0; g < 4; ++g) {
                int row = m0 + wr0 + r * 16 + erow + g;
                int col = n0 + wc0 + c * 16 + ecol;
                if (BF16_OUT)
                    ((unsigned short*)Cout)[(size_t)row * N + col] = f2b(acc[r][c][g]);
                else
                    ((float*)Cout)[(size_t)row * N + col] = acc[r][c][g];
            }
}

// ---------------------------------------------------------------------------
// All four weight transpose-casts in one launch. fp32 [2048][N] -> bf16 [N][2048].
// ---------------------------------------------------------------------------
__global__ __launch_bounds__(256) void transpose_cast_all(const float* __restrict__ Wq,
                                                          const float* __restrict__ Wk,
                                                          const float* __restrict__ Wv,
                                                          const float* __restrict__ Wo,
                                                          unsigned short* __restrict__ Wt,
                                                          unsigned short* __restrict__ Wot) {
    __shared__ float t[32][33];
    int bx = blockIdx.x;
    const float* src; unsigned short* dst; int N, nb;
    if (bx < 64)      { src = Wq; dst = Wt;                          N = 2048; nb = bx; }
    else if (bx < 80) { src = Wk; dst = Wt + (size_t)2048 * DMODEL;  N = 512;  nb = bx - 64; }
    else if (bx < 96) { src = Wv; dst = Wt + (size_t)2560 * DMODEL;  N = 512;  nb = bx - 80; }
    else              { src = Wo; dst = Wot;                         N = 2048; nb = bx - 96; }
    const int n0 = nb * 32, k0 = blockIdx.y * 32;
    const int tx = threadIdx.x & 31, ty = threadIdx.x >> 5;
    #pragma unroll
    for (int i = 0; i < 32; i += 8)
        t[ty + i][tx] = src[(size_t)(k0 + ty + i) * N + n0 + tx];
    __syncthreads();
    #pragma unroll
    for (int i = 0; i < 32; i += 8)
        dst[(size_t)(n0 + ty + i) * DMODEL + k0 + tx] = f2b(t[tx][ty + i]);
}

__global__ void cast_f32_to_bf16(const float* __restrict__ src,
                                 unsigned short* __restrict__ dst, int n) {
    int i = (blockIdx.x * 256 + threadIdx.x) * 8;
    if (i >= n) return;
    float4 a = *(const float4*)(src + i);
    float4 b = *(const float4*)(src + i + 4);
    uint4 o;
    o.x = pkbf(a.x, a.y); o.y = pkbf(a.z, a.w);
    o.z = pkbf(b.x, b.y); o.w = pkbf(b.z, b.w);
    *(uint4*)(dst + i) = o;
}

// ---------------------------------------------------------------------------
// Fused in-place RoPE for Q and K (heads 0..31 = Q, scale 0.125; 32..39 = K).
// (Restored standalone pass — fusing into the GEMM epilogue measured worse.)
// ---------------------------------------------------------------------------
__global__ void rope_all(unsigned short* __restrict__ buf) {
    int idx = blockIdx.x * blockDim.x + threadIdx.x;
    int i   = idx & 31;
    int tmp = idx >> 5;
    int hh  = tmp % 40;
    int row = tmp / 40;
    if (row >= ROWS) return;
    float scale = (hh < 32) ? 0.125f : 1.0f;   // 1/sqrt(HDIM) folded into Q (exact pow2)
    int t = row & (SEQ - 1);
    float inv_freq = powf(10000.0f, -(float)i * (1.0f / 32.0f));
    float ang = (float)t * inv_freq;
    float s, c;
    sincosf(ang, &s, &c);
    unsigned short* p = buf + (size_t)row * NQKV + hh * 64 + i;
    float x1 = b2f(p[0]), x2 = b2f(p[32]);
    p[0]  = f2b((x1 * c - x2 * s) * scale);
    p[32] = f2b((x2 * c + x1 * s) * scale);
}

// ---------------------------------------------------------------------------
// MFMA flash attention (causal, GQA) — round-7 verified version (kept).
// Single-barrier double-buffered K/V LDS on the round-2/5 shell; max-free
// softmax; one-tile register prefetch; time-paired tiles (31-px, px).
// LDS 45 KB -> 3 blocks/CU.
// ---------------------------------------------------------------------------
__global__ __launch_bounds__(256, 3) void attn_mfma(const unsigned short* __restrict__ QKV,
                                                    unsigned short* __restrict__ Ctx) {
    __shared__ unsigned short Ks[2][64][72];    // K tile [buf][kpos][hd]
    __shared__ unsigned short Vts[2][64][72];   // V^T tile [buf][hd][kpos]
    __shared__ unsigned short Ps[4][16][72];    // per-wave P [q][kpos]

    const int tid  = threadIdx.x;
    const int wave = tid >> 6;
    const int lane = tid & 63;
    const int px = blockIdx.x;      // pair index 0..15
    const int h  = blockIdx.y;
    const int b  = blockIdx.z;
    const int kvh = h >> 2;

    const int fr = lane & 15;        // frag row/col index
    const int fg = lane >> 4;        // frag k-group (0..3)
    const size_t base = (size_t)(b * SEQ) * NQKV;

    // staging maps (tile-independent)
    const int krow = tid >> 2, kc0 = (tid & 3) * 16;          // K: 1 row, 32 B
    const int vp2 = tid & 31, vh0 = (tid >> 5) * 8;           // V: kpos pair, 8 hd
    const unsigned short* kbase = QKV + base + (size_t)krow * NQKV + 2048 + kvh * HDIM + kc0;
    const unsigned short* vbase = QKV + base + (size_t)(2 * vp2) * NQKV + 2560 + kvh * HDIM + vh0;

    #pragma unroll 1
    for (int t = 0; t < 2; ++t) {
        const int qb = (t == 0) ? (31 - px) : px;   // big tile first
        const int wbase = qb * 64 + wave * 16;

        // Q fragments (B-operand of S^T): B[n=q=fr][k=fg*8..]
        bf16x8 qf[2];
        #pragma unroll
        for (int ks = 0; ks < 2; ++ks)
            qf[ks] = *(const bf16x8*)(QKV + base + (size_t)(wbase + fr) * NQKV
                                      + h * HDIM + ks * 32 + fg * 8);

        float l = 0.f;
        floatx4 acc[4];   // O^T [hd-tile j2]
        #pragma unroll
        for (int j2 = 0; j2 < 4; ++j2)
            #pragma unroll
            for (int g = 0; g < 4; ++g) acc[j2][g] = 0.f;

        const int nkb = qb + 1;

        // prefetch tile 0
        bf16x8 kr0 = *(const bf16x8*)kbase;
        bf16x8 kr1 = *(const bf16x8*)(kbase + 8);
        bf16x8 v0  = *(const bf16x8*)vbase;
        bf16x8 v1  = *(const bf16x8*)(vbase + NQKV);

        for (int kb = 0; kb < nkb; ++kb) {
            const int pb = kb & 1;
            // (1) write current tile into buf[pb] (last read in kb-2, fenced by kb-1's barrier)
            *(bf16x8*)&Ks[pb][krow][kc0]     = kr0;
            *(bf16x8*)&Ks[pb][krow][kc0 + 8] = kr1;
            #pragma unroll
            for (int j = 0; j < 8; ++j) {          // packed-pair transpose write
                unsigned int w = (unsigned int)(unsigned short)v0[j]
                               | ((unsigned int)(unsigned short)v1[j] << 16);
                *(unsigned int*)&Vts[pb][vh0 + j][2 * vp2] = w;
            }
            // (2) issue next tile's global loads (land during this tile's compute)
            {
                int nx = (kb + 1 < nkb) ? kb + 1 : kb;
                const unsigned short* kp = kbase + (size_t)(nx * 64) * NQKV;
                const unsigned short* vp = vbase + (size_t)(nx * 64) * NQKV;
                kr0 = *(const bf16x8*)kp;
                kr1 = *(const bf16x8*)(kp + 8);
                v0  = *(const bf16x8*)vp;
                v1  = *(const bf16x8*)(vp + NQKV);
            }
            // (3) single barrier: makes buf[pb] visible to all waves
            __syncthreads();

            const bool skip = (kb * 64 > wbase + 15);          // tile fully above diagonal
            if (!skip) {
                const bool needMask = (kb * 64 + 63 > wbase);  // tile touches diagonal

                // ---- S^T = K Q^T : D[m=kpos][n=q] ----
                floatx4 sc[4];   // [kpos-tile j]
                #pragma unroll
                for (int j = 0; j < 4; ++j)
                    #pragma unroll
                    for (int g = 0; g < 4; ++g) sc[j][g] = 0.f;
                __builtin_amdgcn_s_setprio(1);
                #pragma unroll
                for (int ks = 0; ks < 2; ++ks) {
                    #pragma unroll
                    for (int j = 0; j < 4; ++j) {
                        bf16x8 kf = *(const bf16x8*)&Ks[pb][j * 16 + fr][ks * 32 + fg * 8];
                        sc[j] = __builtin_amdgcn_mfma_f32_16x16x32_bf16(kf, qf[ks], sc[j], 0, 0, 0);
                    }
                }
                __builtin_amdgcn_s_setprio(0);

                if (needMask) {
                    int qi = wbase + fr;
                    #pragma unroll
                    for (int j = 0; j < 4; ++j)
                        #pragma unroll
                        for (int g = 0; g < 4; ++g) {
                            int kj = kb * 64 + j * 16 + fg * 4 + g;
                            if (kj > qi) sc[j][g] = -1e30f;
                        }
                }

                // ---- exp + per-lane partial l; P -> per-wave LDS (no shuffles) ----
                #pragma unroll
                for (int j = 0; j < 4; ++j) {
                    #pragma unroll
                    for (int g = 0; g < 4; ++g) {
                        float e = __expf(sc[j][g]);   // masked -> exp(-1e30) = 0
                        sc[j][g] = e;
                        l += e;
                    }
                    uint2 w;
                    w.x = pkbf(sc[j][0], sc[j][1]);
                    w.y = pkbf(sc[j][2], sc[j][3]);
                    *(uint2*)&Ps[wave][fr][j * 16 + fg * 4] = w;
                }

                // ---- O^T += V^T P^T : A = V^T[hd][kpos], B = P[q][kpos] ----
                __builtin_amdgcn_s_setprio(1);
                #pragma unroll
                for (int ks = 0; ks < 2; ++ks) {
                    bf16x8 pf = *(const bf16x8*)&Ps[wave][fr][ks * 32 + fg * 8];
                    #pragma unroll
                    for (int j2 = 0; j2 < 4; ++j2) {
                        bf16x8 vf = *(const bf16x8*)&Vts[pb][j2 * 16 + fr][ks * 32 + fg * 8];
                        acc[j2] = __builtin_amdgcn_mfma_f32_16x16x32_bf16(vf, pf, acc[j2], 0, 0, 0);
                    }
                }
                __builtin_amdgcn_s_setprio(0);
            }
        }
        // fence t=0's last reads before t=1 reuses the buffers
        __syncthreads();

        // epilogue: reduce l across the 4 fg-lanes of each q, normalize, store
        {
            float lt = l;
            lt += __shfl_xor(lt, 16);
            lt += __shfl_xor(lt, 32);
            float inv = 1.0f / lt;
            int q = wbase + fr;
            unsigned short* cp = Ctx + (size_t)(b * SEQ + q) * DMODEL + h * HDIM;
            #pragma unroll
            for (int j2 = 0; j2 < 4; ++j2) {
                uint2 w;
                w.x = pkbf(acc[j2][0] * inv, acc[j2][1] * inv);
                w.y = pkbf(acc[j2][2] * inv, acc[j2][3] * inv);
                *(uint2*)(cp + j2 * 16 + fg * 4) = w;
            }
        }
    }
}

// ---------------------------------------------------------------------------
extern "C" void kernel_launch(void* const* d_in, const int* in_sizes, int n_in,
                              void* d_out, int out_size, void* d_ws, size_t ws_size,
                              hipStream_t stream) {
    const float* X  = (const float*)d_in[0];
    const float* Wq = (const float*)d_in[1];
    const float* Wk = (const float*)d_in[2];
    const float* Wv = (const float*)d_in[3];
    const float* Wo = (const float*)d_in[4];
    float* out = (float*)d_out;

    unsigned short* Xb   = (unsigned short*)d_ws;                 // [4096][2048]
    unsigned short* Wt   = Xb + (size_t)ROWS * DMODEL;            // [3072][2048]
    unsigned short* Wot  = Wt + (size_t)NQKV * DMODEL;            // [2048][2048]
    unsigned short* QKVb = Wot + (size_t)DMODEL * DMODEL;         // [4096][3072]
    unsigned short* Ctxb = QKVb + (size_t)ROWS * NQKV;            // [4096][2048]

    cast_f32_to_bf16<<<(ROWS * DMODEL) / (8 * 256), 256, 0, stream>>>(X, Xb, ROWS * DMODEL);
    transpose_cast_all<<<dim3(160, 64), 256, 0, stream>>>(Wq, Wk, Wv, Wo, Wt, Wot);

    mfma_gemm<true><<<dim3(NQKV / 128, ROWS / 128), 256, 0, stream>>>(Xb, Wt, QKVb, ROWS, NQKV, DMODEL);

    rope_all<<<(ROWS * 40 * 32) / 256, 256, 0, stream>>>(QKVb);

    attn_mfma<<<dim3(SEQ / 128, NHEADS, BATCH), 256, 0, stream>>>(QKVb, Ctxb);

    mfma_gemm<false><<<dim3(DMODEL / 128, ROWS / 128), 256, 0, stream>>>(Ctxb, Wot, out, ROWS, DMODEL, DMODEL);
}

// Round 10
// 304.747 us; speedup vs baseline: 1.5209x; 1.0726x over previous
//
#include <hip/hip_runtime.h>
#include <hip/hip_bf16.h>

// Problem constants
#define BATCH  2
#define SEQ    2048
#define DMODEL 2048
#define NHEADS 32
#define NKV    8
#define HDIM   64
#define ROWS   (BATCH * SEQ)     // 4096
#define NQKV   3072              // 2048 (Q) + 512 (K) + 512 (V)

typedef __attribute__((ext_vector_type(8))) short bf16x8;   // 8 bf16 = 4 VGPRs (MFMA A/B frag)
typedef __attribute__((ext_vector_type(4))) float floatx4;  // MFMA C/D frag

__device__ __forceinline__ float b2f(unsigned short u) {
    union { unsigned int i; float f; } x; x.i = ((unsigned int)u) << 16; return x.f;
}
__device__ __forceinline__ unsigned short f2b(float f) {
    union { float f; unsigned int i; } x; x.f = f;
    unsigned int r = x.i + 0x7fffu + ((x.i >> 16) & 1u);   // RTN-even
    return (unsigned short)(r >> 16);
}
// packed 2xf32 -> 2xbf16 in one dword (v_cvt_pk_bf16_f32), a in low 16 bits
__device__ __forceinline__ unsigned int pkbf(float a, float b) {
    union { __hip_bfloat162 h; unsigned int u; } x;
    x.h = __float22bfloat162_rn(make_float2(a, b));
    return x.u;
}

// async 16B/lane global->LDS. lds ptr must be wave-uniform; lane i lands at +i*16B.
#define GLD16(g, l) __builtin_amdgcn_global_load_lds( \
    (const __attribute__((address_space(1))) unsigned int*)(g), \
    (__attribute__((address_space(3))) unsigned int*)(l), 16, 0, 0)

// ---------------------------------------------------------------------------
// RoPE cos/sin table: tab[t*32 + i] = (cos(t*f_i), sin(t*f_i)).
// Precise powf/sincosf once (~2us) instead of per-element in hot kernels.
// ---------------------------------------------------------------------------
__global__ void rope_table(float2* __restrict__ tab) {
    int idx = blockIdx.x * 256 + threadIdx.x;   // 65536 = 2048 t x 32 i
    int i = idx & 31, t = idx >> 5;
    float inv = powf(10000.0f, -(float)i * (1.0f / 32.0f));
    float s, c;
    sincosf((float)t * inv, &s, &c);
    tab[idx] = make_float2(c, s);
}

// ---------------------------------------------------------------------------
// bf16 MFMA GEMM: C[M,N] = A[M,K] @ Bt[N,K]^T.
// T4 counted-vmcnt 3-buffer ring (r5 verified WIN) + XCD bijective swizzle
// (r8 verified fine). RoPE fusion: after the K-loop, barrier + stage the
// block's 128x32 float2 table tile into LDS (overlays staging buffers, zero
// extra LDS), barrier, rotate in-register. Quadrant mapping validated r6/r7.
// ROUND 10 FIX: r9's staging loop copied only 4 float4 per thread — a
// half-row is 16 float2 = 8 float4. u<4 -> u<8 (256 thr x 128 B = 32 KB ✓).
// ---------------------------------------------------------------------------
template <bool BF16_OUT, bool DO_ROPE>
__global__ __launch_bounds__(256) void mfma_gemm(const unsigned short* __restrict__ A,
                                                 const unsigned short* __restrict__ Bt,
                                                 void* __restrict__ Cout,
                                                 const float2* __restrict__ rtab,
                                                 int M, int N, int K) {
    __shared__ __align__(16) unsigned char smem[49152];   // As[3]|Bs[3] ; epilogue: rope table
    unsigned short (*As)[4096] = (unsigned short (*)[4096])smem;            // 3 x 8 KB
    unsigned short (*Bs)[4096] = (unsigned short (*)[4096])(smem + 24576);  // 3 x 8 KB

    const int tid  = threadIdx.x;
    const int wave = tid >> 6;
    const int lane = tid & 63;

    // XCD-aware bijective swizzle (nwg % 8 == 0 for both grids: 768, 512)
    const int nwg  = gridDim.x * gridDim.y;
    const int wgid = blockIdx.y * gridDim.x + blockIdx.x;
    const int swz  = (wgid & 7) * (nwg >> 3) + (wgid >> 3);
    const int m0 = (swz / gridDim.x) * 128;
    const int n0 = (swz % gridDim.x) * 128;

    const int wr0 = (wave >> 1) * 64;
    const int wc0 = (wave & 1) * 64;

    const int srow = wave * 32 + (lane >> 2);
    const int skc  = (lane & 3) * 8;
    const unsigned short* Ap0 = A  + (size_t)(m0 + srow) * K + skc;
    const unsigned short* Ap1 = Ap0 + (size_t)16 * K;
    const unsigned short* Bp0 = Bt + (size_t)(n0 + srow) * K + skc;
    const unsigned short* Bp1 = Bp0 + (size_t)16 * K;

    const int fr = lane & 15;
    const int fk = (lane >> 4) * 8;

    floatx4 acc[4][4];
    #pragma unroll
    for (int r = 0; r < 4; ++r)
        #pragma unroll
        for (int c = 0; c < 4; ++c)
            #pragma unroll
            for (int g = 0; g < 4; ++g) acc[r][c][g] = 0.f;

    const int NT = K >> 5;   // K-steps of 32

    auto stage = [&](int t, int buf) {
        unsigned short* Ab = &As[buf][wave * 1024];
        unsigned short* Bb = &Bs[buf][wave * 1024];
        const int k0 = t * 32;
        GLD16(Ap0 + k0, Ab);
        GLD16(Ap1 + k0, Ab + 512);
        GLD16(Bp0 + k0, Bb);
        GLD16(Bp1 + k0, Bb + 512);
    };

    // prologue: tiles 0,1 in flight; wait tile 0 only (tile 1 keeps flying)
    stage(0, 0);
    stage(1, 1);
    asm volatile("s_waitcnt vmcnt(4)" ::: "memory");
    __builtin_amdgcn_s_barrier();
    __builtin_amdgcn_sched_barrier(0);

    int cur = 0, nx2 = 2;
    for (int T = 0; T < NT; ++T) {
        if (T + 2 < NT) stage(T + 2, nx2);   // buf holds tile T-1; reads done per prior barrier

        const unsigned short* Asb = &As[cur][0];
        const unsigned short* Bsb = &Bs[cur][0];
        bf16x8 af[4], bfr[4];
        #pragma unroll
        for (int r = 0; r < 4; ++r)
            af[r] = *(const bf16x8*)&Asb[(wr0 + r * 16 + fr) * 32 + fk];
        #pragma unroll
        for (int c = 0; c < 4; ++c)
            bfr[c] = *(const bf16x8*)&Bsb[(wc0 + c * 16 + fr) * 32 + fk];
        #pragma unroll
        for (int r = 0; r < 4; ++r)
            #pragma unroll
            for (int c = 0; c < 4; ++c)
                acc[r][c] = __builtin_amdgcn_mfma_f32_16x16x32_bf16(af[r], bfr[c], acc[r][c], 0, 0, 0);

        if (T + 1 < NT) {
            if (T + 2 < NT)
                asm volatile("s_waitcnt vmcnt(4)" ::: "memory");  // T+1 landed; T+2 flying
            else
                asm volatile("s_waitcnt vmcnt(0)" ::: "memory");  // last tile (once)
            __builtin_amdgcn_s_barrier();
            __builtin_amdgcn_sched_barrier(0);
        }
        cur = (cur == 2) ? 0 : cur + 1;
        nx2 = (nx2 == 2) ? 0 : nx2 + 1;
    }

    const int erow = (lane >> 4) * 4;
    const int ecol = lane & 15;

    if (DO_ROPE) {
        // All waves done reading As/Bs fragments -> safe to overlay the table.
        __syncthreads();
        float2* tab = (float2*)smem;                       // [128][32] = 32 KB
        {
            int lr = tid >> 1, hf = (tid & 1) * 16;        // half-row = 16 float2 = 8 float4
            int t  = (m0 + lr) & (SEQ - 1);
            const float4* src = (const float4*)(rtab + (size_t)t * 32 + hf);
            float4* dst = (float4*)(tab + lr * 32 + hf);
            #pragma unroll
            for (int u = 0; u < 8; ++u) dst[u] = src[u];   // r10 fix: was u<4 (half the table)
        }
        __syncthreads();

        const int colb = n0 + wc0;          // multiple of 64 -> one head, one of Q/K/V
        if (colb < 2560) {                  // Q or K head (V untouched)
            const float scale = (colb < 2048) ? 0.125f : 1.0f;  // 1/sqrt(64) folded into Q
            #pragma unroll
            for (int r = 0; r < 4; ++r)
                #pragma unroll
                for (int g = 0; g < 4; ++g) {
                    int lr = wr0 + r * 16 + erow + g;       // block-local row
                    float2 cs0 = tab[lr * 32 + ecol];
                    float2 cs1 = tab[lr * 32 + ecol + 16];
                    float a0 = acc[r][0][g], a2 = acc[r][2][g];   // dims (ecol, ecol+32)
                    acc[r][0][g] = (a0 * cs0.x - a2 * cs0.y) * scale;
                    acc[r][2][g] = (a2 * cs0.x + a0 * cs0.y) * scale;
                    float a1 = acc[r][1][g], a3 = acc[r][3][g];   // dims (ecol+16, ecol+48)
                    acc[r][1][g] = (a1 * cs1.x - a3 * cs1.y) * scale;
                    acc[r][3][g] = (a3 * cs1.x + a1 * cs1.y) * scale;
                }
        }
    }

    #pragma unroll
    for (int r = 0; r < 4; ++r)
        #pragma unroll
        for (int c = 0; c < 4; ++c)
            #pragma unroll
            for (int g = 0; g < 4; ++g) {
                int row = m0 + wr0 + r * 16 + erow + g;
                int col = n0 + wc0 + c * 16 + ecol;
                if (BF16_OUT)
                    ((unsigned short*)Cout)[(size_t)row * N + col] = f2b(acc[r][c][g]);
                else
                    ((float*)Cout)[(size_t)row * N + col] = acc[r][c][g];
            }
}

// ---------------------------------------------------------------------------
// All four weight transpose-casts in one launch. fp32 [2048][N] -> bf16 [N][2048].
// ---------------------------------------------------------------------------
__global__ __launch_bounds__(256) void transpose_cast_all(const float* __restrict__ Wq,
                                                          const float* __restrict__ Wk,
                                                          const float* __restrict__ Wv,
                                                          const float* __restrict__ Wo,
                                                          unsigned short* __restrict__ Wt,
                                                          unsigned short* __restrict__ Wot) {
    __shared__ float t[32][33];
    int bx = blockIdx.x;
    const float* src; unsigned short* dst; int N, nb;
    if (bx < 64)      { src = Wq; dst = Wt;                          N = 2048; nb = bx; }
    else if (bx < 80) { src = Wk; dst = Wt + (size_t)2048 * DMODEL;  N = 512;  nb = bx - 64; }
    else if (bx < 96) { src = Wv; dst = Wt + (size_t)2560 * DMODEL;  N = 512;  nb = bx - 80; }
    else              { src = Wo; dst = Wot;                         N = 2048; nb = bx - 96; }
    const int n0 = nb * 32, k0 = blockIdx.y * 32;
    const int tx = threadIdx.x & 31, ty = threadIdx.x >> 5;
    #pragma unroll
    for (int i = 0; i < 32; i += 8)
        t[ty + i][tx] = src[(size_t)(k0 + ty + i) * N + n0 + tx];
    __syncthreads();
    #pragma unroll
    for (int i = 0; i < 32; i += 8)
        dst[(size_t)(n0 + ty + i) * DMODEL + k0 + tx] = f2b(t[tx][ty + i]);
}

__global__ void cast_f32_to_bf16(const float* __restrict__ src,
                                 unsigned short* __restrict__ dst, int n) {
    int i = (blockIdx.x * 256 + threadIdx.x) * 8;
    if (i >= n) return;
    float4 a = *(const float4*)(src + i);
    float4 b = *(const float4*)(src + i + 4);
    uint4 o;
    o.x = pkbf(a.x, a.y); o.y = pkbf(a.z, a.w);
    o.z = pkbf(b.x, b.y); o.w = pkbf(b.z, b.w);
    *(uint4*)(dst + i) = o;
}

// ---------------------------------------------------------------------------
// MFMA flash attention (causal, GQA) — ROUND-2 VERSION EXACT (best measured:
// 78.1us, occupancy 35%, verified 3x). 256-thr blocks, 4 waves x 16 q-rows
// over a 64-row tile, time-paired tiles (31-px, px) -> uniform 33 k-iters,
// 1024 blocks, LDS 27.6 KB -> 5 blocks/CU. Max-free softmax, one-tile
// register prefetch, 2 barriers/iter.
// ---------------------------------------------------------------------------
__global__ __launch_bounds__(256, 5) void attn_mfma(const unsigned short* __restrict__ QKV,
                                                    unsigned short* __restrict__ Ctx) {
    __shared__ unsigned short Ks[64][72];    // K tile [kpos][hd]
    __shared__ unsigned short Vts[64][72];   // V^T tile [hd][kpos]
    __shared__ unsigned short Ps[4][16][72]; // per-wave P [q][kpos]

    const int tid  = threadIdx.x;
    const int wave = tid >> 6;
    const int lane = tid & 63;
    const int px = blockIdx.x;      // pair index 0..15
    const int h  = blockIdx.y;
    const int b  = blockIdx.z;
    const int kvh = h >> 2;

    const int fr = lane & 15;        // frag row/col index
    const int fg = lane >> 4;        // frag k-group (0..3)
    const size_t base = (size_t)(b * SEQ) * NQKV;

    // staging maps (tile-independent)
    const int krow = tid >> 2, kc0 = (tid & 3) * 16;          // K: 1 row, 32 B
    const int vp2 = tid & 31, vh0 = (tid >> 5) * 8;           // V: kpos pair, 8 hd
    const unsigned short* kbase = QKV + base + (size_t)krow * NQKV + 2048 + kvh * HDIM + kc0;
    const unsigned short* vbase = QKV + base + (size_t)(2 * vp2) * NQKV + 2560 + kvh * HDIM + vh0;

    #pragma unroll 1
    for (int t = 0; t < 2; ++t) {
        const int qb = (t == 0) ? (31 - px) : px;   // big tile first
        const int wbase = qb * 64 + wave * 16;

        // Q fragments (B-operand of S^T): B[n=q=fr][k=fg*8..]
        bf16x8 qf[2];
        #pragma unroll
        for (int ks = 0; ks < 2; ++ks)
            qf[ks] = *(const bf16x8*)(QKV + base + (size_t)(wbase + fr) * NQKV
                                      + h * HDIM + ks * 32 + fg * 8);

        float l = 0.f;
        floatx4 acc[4];   // O^T [hd-tile j2]
        #pragma unroll
        for (int j2 = 0; j2 < 4; ++j2)
            #pragma unroll
            for (int g = 0; g < 4; ++g) acc[j2][g] = 0.f;

        const int nkb = qb + 1;

        // prefetch tile 0
        bf16x8 kr0 = *(const bf16x8*)kbase;
        bf16x8 kr1 = *(const bf16x8*)(kbase + 8);
        bf16x8 v0  = *(const bf16x8*)vbase;
        bf16x8 v1  = *(const bf16x8*)(vbase + NQKV);

        for (int kb = 0; kb < nkb; ++kb) {
            __syncthreads();                       // prior iter done reading LDS
            *(bf16x8*)&Ks[krow][kc0]     = kr0;
            *(bf16x8*)&Ks[krow][kc0 + 8] = kr1;
            #pragma unroll
            for (int j = 0; j < 8; ++j) {          // packed-pair transpose write
                unsigned int w = (unsigned int)(unsigned short)v0[j]
                               | ((unsigned int)(unsigned short)v1[j] << 16);
                *(unsigned int*)&Vts[vh0 + j][2 * vp2] = w;
            }
            // issue next tile's global loads (land during this tile's compute)
            {
                int nx = (kb + 1 < nkb) ? kb + 1 : kb;
                const unsigned short* kp = kbase + (size_t)(nx * 64) * NQKV;
                const unsigned short* vp = vbase + (size_t)(nx * 64) * NQKV;
                kr0 = *(const bf16x8*)kp;
                kr1 = *(const bf16x8*)(kp + 8);
                v0  = *(const bf16x8*)vp;
                v1  = *(const bf16x8*)(vp + NQKV);
            }
            __syncthreads();

            const bool skip = (kb * 64 > wbase + 15);          // tile fully above diagonal
            if (!skip) {
                const bool needMask = (kb * 64 + 63 > wbase);  // tile touches diagonal

                // ---- S^T = K Q^T : D[m=kpos][n=q] ----
                floatx4 sc[4];   // [kpos-tile j]
                #pragma unroll
                for (int j = 0; j < 4; ++j)
                    #pragma unroll
                    for (int g = 0; g < 4; ++g) sc[j][g] = 0.f;
                __builtin_amdgcn_s_setprio(1);
                #pragma unroll
                for (int ks = 0; ks < 2; ++ks) {
                    #pragma unroll
                    for (int j = 0; j < 4; ++j) {
                        bf16x8 kf = *(const bf16x8*)&Ks[j * 16 + fr][ks * 32 + fg * 8];
                        sc[j] = __builtin_amdgcn_mfma_f32_16x16x32_bf16(kf, qf[ks], sc[j], 0, 0, 0);
                    }
                }
                __builtin_amdgcn_s_setprio(0);

                if (needMask) {
                    int qi = wbase + fr;
                    #pragma unroll
                    for (int j = 0; j < 4; ++j)
                        #pragma unroll
                        for (int g = 0; g < 4; ++g) {
                            int kj = kb * 64 + j * 16 + fg * 4 + g;
                            if (kj > qi) sc[j][g] = -1e30f;
                        }
                }

                // ---- exp + per-lane partial l; P -> per-wave LDS (no shuffles) ----
                #pragma unroll
                for (int j = 0; j < 4; ++j) {
                    #pragma unroll
                    for (int g = 0; g < 4; ++g) {
                        float e = __expf(sc[j][g]);   // masked -> exp(-1e30) = 0
                        sc[j][g] = e;
                        l += e;
                    }
                    uint2 w;
                    w.x = pkbf(sc[j][0], sc[j][1]);
                    w.y = pkbf(sc[j][2], sc[j][3]);
                    *(uint2*)&Ps[wave][fr][j * 16 + fg * 4] = w;
                }

                // ---- O^T += V^T P^T : A = V^T[hd][kpos], B = P[q][kpos] ----
                __builtin_amdgcn_s_setprio(1);
                #pragma unroll
                for (int ks = 0; ks < 2; ++ks) {
                    bf16x8 pf = *(const bf16x8*)&Ps[wave][fr][ks * 32 + fg * 8];
                    #pragma unroll
                    for (int j2 = 0; j2 < 4; ++j2) {
                        bf16x8 vf = *(const bf16x8*)&Vts[j2 * 16 + fr][ks * 32 + fg * 8];
                        acc[j2] = __builtin_amdgcn_mfma_f32_16x16x32_bf16(vf, pf, acc[j2], 0, 0, 0);
                    }
                }
                __builtin_amdgcn_s_setprio(0);
            }
        }

        // epilogue: reduce l across the 4 fg-lanes of each q, normalize, store
        {
            float lt = l;
            lt += __shfl_xor(lt, 16);
            lt += __shfl_xor(lt, 32);
            float inv = 1.0f / lt;
            int q = wbase + fr;
            unsigned short* cp = Ctx + (size_t)(b * SEQ + q) * DMODEL + h * HDIM;
            #pragma unroll
            for (int j2 = 0; j2 < 4; ++j2) {
                uint2 w;
                w.x = pkbf(acc[j2][0] * inv, acc[j2][1] * inv);
                w.y = pkbf(acc[j2][2] * inv, acc[j2][3] * inv);
                *(uint2*)(cp + j2 * 16 + fg * 4) = w;
            }
        }
    }
}

// ---------------------------------------------------------------------------
extern "C" void kernel_launch(void* const* d_in, const int* in_sizes, int n_in,
                              void* d_out, int out_size, void* d_ws, size_t ws_size,
                              hipStream_t stream) {
    const float* X  = (const float*)d_in[0];
    const float* Wq = (const float*)d_in[1];
    const float* Wk = (const float*)d_in[2];
    const float* Wv = (const float*)d_in[3];
    const float* Wo = (const float*)d_in[4];
    float* out = (float*)d_out;

    unsigned short* Xb   = (unsigned short*)d_ws;                 // [4096][2048]
    unsigned short* Wt   = Xb + (size_t)ROWS * DMODEL;            // [3072][2048]
    unsigned short* Wot  = Wt + (size_t)NQKV * DMODEL;            // [2048][2048]
    unsigned short* QKVb = Wot + (size_t)DMODEL * DMODEL;         // [4096][3072]
    unsigned short* Ctxb = QKVb + (size_t)ROWS * NQKV;            // [4096][2048]
    float2* Rtab = (float2*)(Ctxb + (size_t)ROWS * DMODEL);       // [2048][32] cos/sin

    rope_table<<<256, 256, 0, stream>>>(Rtab);
    cast_f32_to_bf16<<<(ROWS * DMODEL) / (8 * 256), 256, 0, stream>>>(X, Xb, ROWS * DMODEL);
    transpose_cast_all<<<dim3(160, 64), 256, 0, stream>>>(Wq, Wk, Wv, Wo, Wt, Wot);

    // QKV projection with fused LDS-table RoPE (replaces the rope_all pass)
    mfma_gemm<true, true><<<dim3(NQKV / 128, ROWS / 128), 256, 0, stream>>>(Xb, Wt, QKVb, Rtab, ROWS, NQKV, DMODEL);

    attn_mfma<<<dim3(SEQ / 128, NHEADS, BATCH), 256, 0, stream>>>(QKVb, Ctxb);

    mfma_gemm<false, false><<<dim3(DMODEL / 128, ROWS / 128), 256, 0, stream>>>(Ctxb, Wot, out, Rtab, ROWS, DMODEL, DMODEL);
}